// Round 14
// baseline (3945.670 us; speedup 1.0000x reference)
//
#include <hip/hip_runtime.h>

typedef __attribute__((ext_vector_type(8))) short short8;
typedef __attribute__((ext_vector_type(4))) float f32x4;
typedef unsigned short u16;
typedef unsigned long long u64;

#define TP   1022      // conv output length = T-2
#define NWRK 32        // worker WGs (one XCD): 2 batch-groups x 16

// ws layout (byte offsets, all 256-aligned)
#define OFF_WPACK   0            // 2048*576*2   = 2359296
#define OFF_SEQ     2359296      // 1022*64*64*2 = 8372224
#define OFF_BIAS    10993664     // 2048*4       = 8192
#define OFF_H0      11001856     // 64*512*2     = 65536
#define OFF_H1      11067392     // 64*512*2     = 65536
#define OFF_HFIN    11132928     // 64*512*4     = 131072
#define OFF_BAR     11264000
// bar u32 idx: grp0 cnt @0 | xcdcnt @8..15 | designated @16 (setup-only, shares
// line with grp0 cnt) | grp1 cnt @32 | keeper-done @96  (separate 128B lines)

__device__ inline u16 f2bf(float x) {
  union { float f; unsigned u; } un; un.f = x;
  unsigned r = un.u + 0x7fffu + ((un.u >> 16) & 1u);  // RNE
  return (u16)(r >> 16);
}
__device__ inline float sigmoidf_(float x) { return 1.f / (1.f + __expf(-x)); }
__device__ inline float tanhf_(float x)    { return 2.f / (1.f + __expf(-2.f * x)) - 1.f; }

// 16B load/store served by the XCD-local L2 (sc0 bypasses L1 — required because
// h lines are re-read every 2 steps and would otherwise hit stale L1 data).
__device__ inline f32x4 load16_sc0(const void* p) {
  f32x4 r;
  asm volatile("global_load_dwordx4 %0, %1, off sc0" : "=v"(r) : "v"(p) : "memory");
  return r;
}
__device__ inline void store16_sc0(void* p, f32x4 v) {
  asm volatile("global_store_dwordx4 %0, %1, off sc0" :: "v"(p), "v"(v) : "memory");
}

// ---- init: zero h buffers + barrier region, build packed bias (b_ih+b_hh, n=4j+g)
__global__ void k_init(const float* __restrict__ b_ih, const float* __restrict__ b_hh,
                       float* __restrict__ biasp, unsigned* __restrict__ hzero,
                       unsigned* __restrict__ bar) {
  int tid = blockIdx.x * 256 + threadIdx.x;
  if (tid < 32768) hzero[tid] = 0u;                 // both h bufs (131072 B)
  if (tid < 2048) {
    int j = tid >> 2, g = tid & 3;
    int row = g * 512 + j;
    biasp[tid] = b_ih[row] + b_hh[row];
  }
  if (tid < 128) bar[tid] = 0u;                     // counters + xcdcnt + designated + done
}

// ---- pack W = [w_ih ; w_hh] (2048 x 576) into MFMA A-fragment order, bf16.
__global__ void k_pack(const float* __restrict__ w_ih, const float* __restrict__ w_hh,
                       u16* __restrict__ wp) {
  int idx = blockIdx.x * 256 + threadIdx.x;        // < 128*18*512 = 1179648
  int nt = idx / 9216;
  int rem = idx - nt * 9216;
  int kt = rem / 512;
  int rem2 = rem - kt * 512;
  int lane = rem2 >> 3, i = rem2 & 7;
  int n = nt * 16 + (lane & 15);
  int k = kt * 32 + (lane >> 4) * 8 + i;
  int j = n >> 2, g = n & 3;
  int row = g * 512 + j;
  float v = (k < 64) ? w_ih[row * 64 + k] : w_hh[row * 512 + (k - 64)];
  wp[idx] = f2bf(v);
}

// ---- normalize (fused) + conv1d(k=3, VALID) + relu -> seq[t][b][oc] bf16
__global__ __launch_bounds__(256) void k_conv(const float* __restrict__ inX,
                                              const float* __restrict__ conv_w,
                                              const float* __restrict__ conv_b,
                                              u16* __restrict__ seq) {
  __shared__ float xn[6][128];
  __shared__ float rn[6];
  int b = blockIdx.y;
  int t0 = blockIdx.x * 4;
  int tid = threadIdx.x;
  for (int e = tid; e < 768; e += 256) {
    int ri = e >> 7, col = e & 127;
    int t = t0 + ri;
    xn[ri][col] = (t < 1024) ? inX[((size_t)b * 1024 + t) * 128 + col] : 0.f;
  }
  __syncthreads();
  if (tid < 192) {                                 // 6 rows x 32 lanes
    int ri = tid >> 5, l32 = tid & 31;
    float4 v = *reinterpret_cast<const float4*>(&xn[ri][l32 * 4]);
    float s = v.x * v.x + v.y * v.y + v.z * v.z + v.w * v.w;
    #pragma unroll
    for (int d = 1; d < 32; d <<= 1) s += __shfl_xor(s, d, 32);
    if (l32 == 0) rn[ri] = 1.f / fmaxf(sqrtf(s), 1e-12f);
  }
  __syncthreads();
  for (int e = tid; e < 768; e += 256) {
    int ri = e >> 7, col = e & 127;
    xn[ri][col] *= rn[ri];
  }
  __syncthreads();
  int oc = tid & 63, ty = tid >> 6;
  int t = t0 + ty;
  if (t < TP) {
    const float* wr = conv_w + oc * 384;           // (OC, IN, 3) row-major
    float s = conv_b[oc];
    #pragma unroll 4
    for (int i = 0; i < 128; ++i) {
      s += wr[i * 3 + 0] * xn[ty + 0][i]
         + wr[i * 3 + 1] * xn[ty + 1][i]
         + wr[i * 3 + 2] * xn[ty + 2][i];
    }
    s = fmaxf(s, 0.f);
    seq[((size_t)t * 64 + b) * 64 + oc] = f2bf(s);
  }
}

// ---- persistent LSTM on ONE XCD, 2 independent batch-groups of 16 WGs.
// vs round 13 (passing): (1) TRUE per-group counters (16-WG sync, groups fully
// decoupled — disjoint batches/h-regions, same proven poll/signal pattern);
// (2) K-split staging: wait only cols 0..511B before computing kt 0..7; the
// other half's L2 latency hides under the first 8 k-tiles' MFMAs.
__global__ __launch_bounds__(256, 1) void k_lstm(const u16* __restrict__ seq,
                                                 const u16* __restrict__ wp,
                                                 const float* __restrict__ biasp,
                                                 u16* h0buf, u16* h1buf,
                                                 float* __restrict__ hfin,
                                                 unsigned* bar) {
  const int tid = threadIdx.x;
  __shared__ int s_rank;
  __shared__ __align__(16) char hl[32768];         // staged group h-half, swizzled
  __shared__ u16 ostage[32][40];                   // [batch_local][unit_local], padded

  // ---- XCD self-designation (setup only; agent-scope atomics via MALL)
  if (tid == 0) {
    unsigned xcd;
    asm volatile("s_getreg_b32 %0, hwreg(HW_REG_XCC_ID)" : "=s"(xcd));
    xcd &= 7u;
    unsigned r = __hip_atomic_fetch_add(&bar[8 + xcd], 1u, __ATOMIC_RELAXED,
                                        __HIP_MEMORY_SCOPE_AGENT);
    if (r == NWRK - 1) {
      unsigned expected = 0u;
      __hip_atomic_compare_exchange_strong(&bar[16], &expected, xcd + 1u,
                                           __ATOMIC_RELAXED, __ATOMIC_RELAXED,
                                           __HIP_MEMORY_SCOPE_AGENT);
    }
    unsigned d;
    while ((d = __hip_atomic_load(&bar[16], __ATOMIC_RELAXED,
                                  __HIP_MEMORY_SCOPE_AGENT)) == 0u)
      __builtin_amdgcn_s_sleep(8);
    s_rank = (xcd == d - 1u && r < NWRK) ? (int)r : -1;
  }
  __syncthreads();
  const int rank = s_rank;

  if (rank < 0) {
    // ---- clock keeper: dependent-FMA spin until all workers signal done.
    const int lane_ = tid & 63;
    float x = (float)tid + 1.0f;
    unsigned d = 0;
    do {
      #pragma unroll
      for (int i = 0; i < 1024; ++i) x = __builtin_fmaf(x, 1.0000001f, 1.0e-30f);
      asm volatile("" :: "v"(x));                  // keep the chain live (no DCE)
      if (lane_ == 0)
        d = __hip_atomic_fetch_add(&bar[96], 0u, __ATOMIC_RELAXED,
                                   __HIP_MEMORY_SCOPE_AGENT);
      d = __shfl(d, 0);
    } while (d < NWRK);
    return;
  }

  const int wave = tid >> 6, lane = tid & 63;
  const int g   = rank >> 4;                       // batch group 0/1
  const int wgi = rank & 15;                       // index within group
  const int B0  = g * 32;                          // group's batch base
  const int U0  = wgi * 32;                        // WG's unit base
  const int mt2 = wgi * 4 + wave;                  // 0..63 within group
  const int mtA = 2 * mt2, mtB = mtA + 1;          // unit m-tiles 0..127
  const int bl  = lane & 15;                       // local batch (tile 0); +16 tile 1
  const int bA  = B0 + bl;                         // global batch (tile 0)
  const int hi  = lane >> 4;                       // 0..3
  const int koff = hi * 8;
  const int ulA = 8 * wave + hi;                   // unit-local in WG's 32-slice
  const int ulB = ulA + 4;
  const int uA  = U0 + ulA;                        // global unit ids
  const int uB  = U0 + ulB;
  const float4 biasA = *reinterpret_cast<const float4*>(biasp + mtA * 16 + hi * 4);
  const float4 biasB = *reinterpret_cast<const float4*>(biasp + mtB * 16 + hi * 4);

  // preload both weight slices: 2 x 18 k-tiles x 8 bf16/lane = 144 VGPRs
  short8 wA[18], wB[18];
  {
    const u16* wa = wp + (size_t)mtA * (18 * 512) + lane * 8;
    const u16* wb = wp + (size_t)mtB * (18 * 512) + lane * 8;
    #pragma unroll
    for (int kt = 0; kt < 18; ++kt) {
      wA[kt] = *reinterpret_cast<const short8*>(wa + kt * 512);
      wB[kt] = *reinterpret_cast<const short8*>(wb + kt * 512);
    }
  }

  unsigned* grpcnt = &bar[g * 32];                 // per-group counter (own 128B line)
  float cA0 = 0.f, cA1 = 0.f, cB0 = 0.f, cB1 = 0.f;
  f32x4 accA0, accA1, accB0, accB1;

  // LDS fragment-read constants (local rows bl / bl+16; swizzle by row&7)
  const int r0base = bl * 1024;
  const int r1base = r0base + 16 * 1024;
  const int rmask  = (bl & 7) << 4;                // (bl+16)&7 == bl&7
  const int fr_hib = hi * 16;

  // staging constants: rows p*8+strow, col-16B stcol; swizzle=(row&7)<<4=strow<<4
  const int strow = tid >> 5;                      // 0..7
  const int stcol = tid & 31;                      // 16B chunk within 512B half
  const int stswz = strow << 4;

#define XPART(T) do { \
    const u16* xt_ = seq + (size_t)(T) * 4096; \
    short8 x0a = *reinterpret_cast<const short8*>(xt_ + bA * 64 + koff); \
    short8 x1a = *reinterpret_cast<const short8*>(xt_ + (bA + 16) * 64 + koff); \
    short8 x0b = *reinterpret_cast<const short8*>(xt_ + bA * 64 + 32 + koff); \
    short8 x1b = *reinterpret_cast<const short8*>(xt_ + (bA + 16) * 64 + 32 + koff); \
    f32x4 z_ = {0.f, 0.f, 0.f, 0.f}; \
    accA0 = __builtin_amdgcn_mfma_f32_16x16x32_bf16(wA[0], x0a, z_, 0, 0, 0); \
    accA1 = __builtin_amdgcn_mfma_f32_16x16x32_bf16(wA[0], x1a, z_, 0, 0, 0); \
    accB0 = __builtin_amdgcn_mfma_f32_16x16x32_bf16(wB[0], x0a, z_, 0, 0, 0); \
    accB1 = __builtin_amdgcn_mfma_f32_16x16x32_bf16(wB[0], x1a, z_, 0, 0, 0); \
    accA0 = __builtin_amdgcn_mfma_f32_16x16x32_bf16(wA[1], x0b, accA0, 0, 0, 0); \
    accA1 = __builtin_amdgcn_mfma_f32_16x16x32_bf16(wA[1], x1b, accA1, 0, 0, 0); \
    accB0 = __builtin_amdgcn_mfma_f32_16x16x32_bf16(wB[1], x0b, accB0, 0, 0, 0); \
    accB1 = __builtin_amdgcn_mfma_f32_16x16x32_bf16(wB[1], x1b, accB1, 0, 0, 0); \
  } while (0)

  XPART(0);                                        // x-part for t=0 (h(-1)=0)

  for (int t = 0; t < TP; ++t) {
    // ---- wait for own group's h(t-1): ONE RMW per WG per poll iteration
    if (t > 0) {
      if (tid == 0) {
        const unsigned tgt = (unsigned)(16 * t);
        for (;;) {
          unsigned v = __hip_atomic_fetch_add(grpcnt, 0u, __ATOMIC_RELAXED,
                                              __HIP_MEMORY_SCOPE_WORKGROUP);
          if (v >= tgt) break;
          __builtin_amdgcn_s_sleep(1);
        }
      }
      __syncthreads();
    }

    const u16* hc = (t & 1) ? h1buf : h0buf;
    u16* hn = (t & 1) ? h0buf : h1buf;

    // ---- stage the GROUP's 32KB h-half, K-SPLIT: issue all 8 loads, wait only
    // the first-half columns (bytes 0..511 of each row), write+barrier, compute
    // kt 0..7 while the second half's latency hides; then write+barrier, kt 8..15.
    const u16* hsrc = hc + (size_t)B0 * 512;
    f32x4 va[4], vb[4];
    #pragma unroll
    for (int p = 0; p < 4; ++p)
      va[p] = load16_sc0(hsrc + (size_t)(p * 8 + strow) * 512 + stcol * 8);
    #pragma unroll
    for (int p = 0; p < 4; ++p)
      vb[p] = load16_sc0(hsrc + (size_t)(p * 8 + strow) * 512 + 256 + stcol * 8);
    asm volatile("s_waitcnt vmcnt(4)" ::: "memory");
    __builtin_amdgcn_sched_barrier(0);
    #pragma unroll
    for (int p = 0; p < 4; ++p)
      *reinterpret_cast<f32x4*>(hl + (p * 8 + strow) * 1024 +
                                ((stcol * 16) ^ stswz)) = va[p];
    __syncthreads();

    // ---- kt 0..7 (columns 0..511B, region A)
    #pragma unroll
    for (int kt = 0; kt < 8; ++kt) {
      int off = (kt * 64 + fr_hib) ^ rmask;
      short8 b0 = *reinterpret_cast<const short8*>(hl + r0base + off);
      short8 b1 = *reinterpret_cast<const short8*>(hl + r1base + off);
      accA0 = __builtin_amdgcn_mfma_f32_16x16x32_bf16(wA[kt + 2], b0, accA0, 0, 0, 0);
      accA1 = __builtin_amdgcn_mfma_f32_16x16x32_bf16(wA[kt + 2], b1, accA1, 0, 0, 0);
      accB0 = __builtin_amdgcn_mfma_f32_16x16x32_bf16(wB[kt + 2], b0, accB0, 0, 0, 0);
      accB1 = __builtin_amdgcn_mfma_f32_16x16x32_bf16(wB[kt + 2], b1, accB1, 0, 0, 0);
    }

    // ---- write second half (long arrived), barrier, kt 8..15 (region B)
    asm volatile("s_waitcnt vmcnt(0)" ::: "memory");
    __builtin_amdgcn_sched_barrier(0);
    #pragma unroll
    for (int p = 0; p < 4; ++p)
      *reinterpret_cast<f32x4*>(hl + (p * 8 + strow) * 1024 + 512 +
                                ((stcol * 16) ^ stswz)) = vb[p];
    __syncthreads();
    #pragma unroll
    for (int kt = 8; kt < 16; ++kt) {
      int off = (kt * 64 + fr_hib) ^ rmask;
      short8 b0 = *reinterpret_cast<const short8*>(hl + r0base + off);
      short8 b1 = *reinterpret_cast<const short8*>(hl + r1base + off);
      accA0 = __builtin_amdgcn_mfma_f32_16x16x32_bf16(wA[kt + 2], b0, accA0, 0, 0, 0);
      accA1 = __builtin_amdgcn_mfma_f32_16x16x32_bf16(wA[kt + 2], b1, accA1, 0, 0, 0);
      accB0 = __builtin_amdgcn_mfma_f32_16x16x32_bf16(wB[kt + 2], b0, accB0, 0, 0, 0);
      accB1 = __builtin_amdgcn_mfma_f32_16x16x32_bf16(wB[kt + 2], b1, accB1, 0, 0, 0);
    }

    // ---- gates (i,f,g,o in acc[0..3] of each lane, per mt x batch-tile)
    float iA0 = sigmoidf_(accA0[0] + biasA.x);
    float fA0 = sigmoidf_(accA0[1] + biasA.y);
    float gA0 = tanhf_(accA0[2] + biasA.z);
    float oA0 = sigmoidf_(accA0[3] + biasA.w);
    cA0 = fA0 * cA0 + iA0 * gA0;
    float hvA0 = oA0 * tanhf_(cA0);
    float iA1 = sigmoidf_(accA1[0] + biasA.x);
    float fA1 = sigmoidf_(accA1[1] + biasA.y);
    float gA1 = tanhf_(accA1[2] + biasA.z);
    float oA1 = sigmoidf_(accA1[3] + biasA.w);
    cA1 = fA1 * cA1 + iA1 * gA1;
    float hvA1 = oA1 * tanhf_(cA1);
    float iB0 = sigmoidf_(accB0[0] + biasB.x);
    float fB0 = sigmoidf_(accB0[1] + biasB.y);
    float gB0 = tanhf_(accB0[2] + biasB.z);
    float oB0 = sigmoidf_(accB0[3] + biasB.w);
    cB0 = fB0 * cB0 + iB0 * gB0;
    float hvB0 = oB0 * tanhf_(cB0);
    float iB1 = sigmoidf_(accB1[0] + biasB.x);
    float fB1 = sigmoidf_(accB1[1] + biasB.y);
    float gB1 = tanhf_(accB1[2] + biasB.z);
    float oB1 = sigmoidf_(accB1[3] + biasB.w);
    cB1 = fB1 * cB1 + iB1 * gB1;
    float hvB1 = oB1 * tanhf_(cB1);

    // ---- stage h slice (32 batches x 32 units) in padded LDS
    ostage[bl][ulA]      = f2bf(hvA0);
    ostage[bl + 16][ulA] = f2bf(hvA1);
    ostage[bl][ulB]      = f2bf(hvB0);
    ostage[bl + 16][ulB] = f2bf(hvB1);
    if (t == TP - 1) {
      hfin[bA * 512 + uA]        = hvA0;
      hfin[(bA + 16) * 512 + uA] = hvA1;
      hfin[bA * 512 + uB]        = hvB0;
      hfin[(bA + 16) * 512 + uB] = hvB1;
    }
    __syncthreads();

    // ---- coalesced sc0 h stores: 128 threads x 16B into XCD L2
    if (tid < 128) {
      int b_l = tid >> 2, q = tid & 3;
      f32x4 val = *reinterpret_cast<const f32x4*>(&ostage[b_l][q * 8]);
      store16_sc0(hn + (size_t)(B0 + b_l) * 512 + U0 + q * 8, val);
    }
    asm volatile("s_waitcnt vmcnt(0)" ::: "memory");
    __syncthreads();                               // all waves' stores drained

    // ---- signal own group: ONE atomic RMW per WG
    if (tid == 0)
      __hip_atomic_fetch_add(grpcnt, 1u, __ATOMIC_RELAXED, __HIP_MEMORY_SCOPE_WORKGROUP);

    // ---- x-part prefetch for t+1 (plain cached loads) overlaps others' polls
    if (t + 1 < TP) XPART(t + 1);
  }
#undef XPART

  // ---- tell the clock keepers we're done (MALL-scope RMW, cross-XCD visible)
  if (tid == 0)
    __hip_atomic_fetch_add(&bar[96], 1u, __ATOMIC_RELAXED, __HIP_MEMORY_SCOPE_AGENT);
}

// ---- final linear: out[b][o] = h . lin_w[o] + lin_b[o]  (fp32)
__global__ void k_fc(const float* __restrict__ hfin, const float* __restrict__ lin_w,
                     const float* __restrict__ lin_b, float* __restrict__ out) {
  int b = blockIdx.x, o = threadIdx.x;             // 128 threads
  const float* hp = hfin + b * 512;
  const float* wq = lin_w + o * 512;
  float s = lin_b[o];
  #pragma unroll 4
  for (int j = 0; j < 512; ++j) s += hp[j] * wq[j];
  out[b * 128 + o] = s;
}

extern "C" void kernel_launch(void* const* d_in, const int* in_sizes, int n_in,
                              void* d_out, int out_size, void* d_ws, size_t ws_size,
                              hipStream_t stream) {
  const float* inX    = (const float*)d_in[0];
  const float* conv_w = (const float*)d_in[2];
  const float* conv_b = (const float*)d_in[3];
  const float* w_ih   = (const float*)d_in[4];
  const float* w_hh   = (const float*)d_in[5];
  const float* b_ih   = (const float*)d_in[6];
  const float* b_hh   = (const float*)d_in[7];
  const float* lin_w  = (const float*)d_in[8];
  const float* lin_b  = (const float*)d_in[9];
  float* out = (float*)d_out;
  char* ws = (char*)d_ws;
  u16*      wpack = (u16*)(ws + OFF_WPACK);
  u16*      seq   = (u16*)(ws + OFF_SEQ);
  float*    biasp = (float*)(ws + OFF_BIAS);
  u16*      h0b   = (u16*)(ws + OFF_H0);
  u16*      h1b   = (u16*)(ws + OFF_H1);
  float*    hfin  = (float*)(ws + OFF_HFIN);
  unsigned* bar   = (unsigned*)(ws + OFF_BAR);

  k_init<<<dim3(128), dim3(256), 0, stream>>>(b_ih, b_hh, biasp, (unsigned*)(ws + OFF_H0), bar);
  k_pack<<<dim3(4608), dim3(256), 0, stream>>>(w_ih, w_hh, wpack);
  k_conv<<<dim3(256, 64), dim3(256), 0, stream>>>(inX, conv_w, conv_b, seq);
  k_lstm<<<dim3(256), dim3(256), 0, stream>>>(seq, wpack, biasp, h0b, h1b, hfin, bar);
  k_fc<<<dim3(64), dim3(128), 0, stream>>>(hfin, lin_w, lin_b, out);
}

// Round 16
// 3458.548 us; speedup vs baseline: 1.1408x; 1.1408x over previous
//
#include <hip/hip_runtime.h>

typedef __attribute__((ext_vector_type(8))) short short8;
typedef __attribute__((ext_vector_type(4))) float f32x4;
typedef unsigned short u16;
typedef unsigned long long u64;

#define TP   1022      // conv output length = T-2
#define NWRK 32        // worker WGs (one XCD): 2 batch-groups x 16

// ws layout (byte offsets, all 256-aligned)
#define OFF_WPACK   0            // 2048*576*2   = 2359296
#define OFF_SEQ     2359296      // 1022*64*64*2 = 8372224
#define OFF_BIAS    10993664     // 2048*4      = 8192
#define OFF_H0      11001856     // 64*512*2     = 65536
#define OFF_H1      11067392     // 64*512*2     = 65536
#define OFF_HFIN    11132928     // 64*512*4     = 131072
#define OFF_BAR     11264000
// bar u32 idx: grp0 cnt @0 | xcdcnt @8..15 | designated @16 | grp1 cnt @32 |
//              keeper-done @96   (separate 128B lines)
#define OFF_CWT     11266048     // transposed conv weights: 384*64*4 = 98304

__device__ inline u16 f2bf(float x) {
  union { float f; unsigned u; } un; un.f = x;
  unsigned r = un.u + 0x7fffu + ((un.u >> 16) & 1u);  // RNE
  return (u16)(r >> 16);
}
__device__ inline float sigmoidf_(float x) { return 1.f / (1.f + __expf(-x)); }
__device__ inline float tanhf_(float x)    { return 2.f / (1.f + __expf(-2.f * x)) - 1.f; }

// 16B load/store served by the XCD-local L2 (sc0 bypasses L1 — required because
// h lines are re-read every 2 steps and would otherwise hit stale L1 data).
__device__ inline f32x4 load16_sc0(const void* p) {
  f32x4 r;
  asm volatile("global_load_dwordx4 %0, %1, off sc0" : "=v"(r) : "v"(p) : "memory");
  return r;
}
__device__ inline void store16_sc0(void* p, f32x4 v) {
  asm volatile("global_store_dwordx4 %0, %1, off sc0" :: "v"(p), "v"(v) : "memory");
}

// ---- init: zero h buffers + barrier region, build packed bias (b_ih+b_hh, n=4j+g)
__global__ void k_init(const float* __restrict__ b_ih, const float* __restrict__ b_hh,
                       float* __restrict__ biasp, unsigned* __restrict__ hzero,
                       unsigned* __restrict__ bar) {
  int tid = blockIdx.x * 256 + threadIdx.x;
  if (tid < 32768) hzero[tid] = 0u;                 // both h bufs (131072 B)
  if (tid < 2048) {
    int j = tid >> 2, g = tid & 3;
    int row = g * 512 + j;
    biasp[tid] = b_ih[row] + b_hh[row];
  }
  if (tid < 128) bar[tid] = 0u;                     // counters + xcdcnt + designated + done
}

// ---- pack W = [w_ih ; w_hh] (2048 x 576) into MFMA A-fragment order, bf16.
__global__ void k_pack(const float* __restrict__ w_ih, const float* __restrict__ w_hh,
                       u16* __restrict__ wp) {
  int idx = blockIdx.x * 256 + threadIdx.x;        // < 128*18*512 = 1179648
  int nt = idx / 9216;
  int rem = idx - nt * 9216;
  int kt = rem / 512;
  int rem2 = rem - kt * 512;
  int lane = rem2 >> 3, i = rem2 & 7;
  int n = nt * 16 + (lane & 15);
  int k = kt * 32 + (lane >> 4) * 8 + i;
  int j = n >> 2, g = n & 3;
  int row = g * 512 + j;
  float v = (k < 64) ? w_ih[row * 64 + k] : w_hh[row * 512 + (k - 64)];
  wp[idx] = f2bf(v);
}

// ---- transpose conv weights: cwT[(i*3+k)*64 + oc] = conv_w[oc][i][k]
// makes k_conv's weight reads lane-coalesced (256B/instruction).
__global__ void k_packc(const float* __restrict__ conv_w, float* __restrict__ cwT) {
  int idx = blockIdx.x * 256 + threadIdx.x;        // < 24576
  if (idx < 24576) {
    int ik = idx >> 6, oc = idx & 63;
    cwT[ik * 64 + oc] = conv_w[oc * 384 + ik];
  }
}

// ---- normalize (fused) + conv1d(k=3, VALID) + relu -> seq[t][b][oc] bf16
// weight reads via transposed cwT: lane (=oc) coalesced, xn reads are LDS
// broadcasts (uniform address across the 64 oc lanes).
__global__ __launch_bounds__(256) void k_conv(const float* __restrict__ inX,
                                              const float* __restrict__ cwT,
                                              const float* __restrict__ conv_b,
                                              u16* __restrict__ seq) {
  __shared__ float xn[6][128];
  __shared__ float rn[6];
  int b = blockIdx.y;
  int t0 = blockIdx.x * 4;
  int tid = threadIdx.x;
  for (int e = tid; e < 768; e += 256) {
    int ri = e >> 7, col = e & 127;
    int t = t0 + ri;
    xn[ri][col] = (t < 1024) ? inX[((size_t)b * 1024 + t) * 128 + col] : 0.f;
  }
  __syncthreads();
  if (tid < 192) {                                 // 6 rows x 32 lanes
    int ri = tid >> 5, l32 = tid & 31;
    float4 v = *reinterpret_cast<const float4*>(&xn[ri][l32 * 4]);
    float s = v.x * v.x + v.y * v.y + v.z * v.z + v.w * v.w;
    #pragma unroll
    for (int d = 1; d < 32; d <<= 1) s += __shfl_xor(s, d, 32);
    if (l32 == 0) rn[ri] = 1.f / fmaxf(sqrtf(s), 1e-12f);
  }
  __syncthreads();
  for (int e = tid; e < 768; e += 256) {
    int ri = e >> 7, col = e & 127;
    xn[ri][col] *= rn[ri];
  }
  __syncthreads();
  int oc = tid & 63, ty = tid >> 6;
  int t = t0 + ty;
  if (t < TP) {
    const float* wt = cwT + oc;                    // lane-coalesced column
    float s = conv_b[oc];
    #pragma unroll 8
    for (int i = 0; i < 128; ++i) {
      s += wt[(i * 3 + 0) * 64] * xn[ty + 0][i]
         + wt[(i * 3 + 1) * 64] * xn[ty + 1][i]
         + wt[(i * 3 + 2) * 64] * xn[ty + 2][i];
    }
    s = fmaxf(s, 0.f);
    seq[((size_t)t * 64 + b) * 64 + oc] = f2bf(s);
  }
}

// ---- persistent LSTM on ONE XCD, 2 independent batch-groups of 16 WGs.
// BYTE-IDENTICAL to the round-14 passing kernel (per-group counters, K-split
// staging with __syncthreads). Three barrier-machinery rewrites (r9/r11/r15)
// all deadlocked while offering <100us — this structure is the proven floor.
__global__ __launch_bounds__(256, 1) void k_lstm(const u16* __restrict__ seq,
                                                 const u16* __restrict__ wp,
                                                 const float* __restrict__ biasp,
                                                 u16* h0buf, u16* h1buf,
                                                 float* __restrict__ hfin,
                                                 unsigned* bar) {
  const int tid = threadIdx.x;
  __shared__ int s_rank;
  __shared__ __align__(16) char hl[32768];         // staged group h-half, swizzled
  __shared__ u16 ostage[32][40];                   // [batch_local][unit_local], padded

  // ---- XCD self-designation (setup only; agent-scope atomics via MALL)
  if (tid == 0) {
    unsigned xcd;
    asm volatile("s_getreg_b32 %0, hwreg(HW_REG_XCC_ID)" : "=s"(xcd));
    xcd &= 7u;
    unsigned r = __hip_atomic_fetch_add(&bar[8 + xcd], 1u, __ATOMIC_RELAXED,
                                        __HIP_MEMORY_SCOPE_AGENT);
    if (r == NWRK - 1) {
      unsigned expected = 0u;
      __hip_atomic_compare_exchange_strong(&bar[16], &expected, xcd + 1u,
                                           __ATOMIC_RELAXED, __ATOMIC_RELAXED,
                                           __HIP_MEMORY_SCOPE_AGENT);
    }
    unsigned d;
    while ((d = __hip_atomic_load(&bar[16], __ATOMIC_RELAXED,
                                  __HIP_MEMORY_SCOPE_AGENT)) == 0u)
      __builtin_amdgcn_s_sleep(8);
    s_rank = (xcd == d - 1u && r < NWRK) ? (int)r : -1;
  }
  __syncthreads();
  const int rank = s_rank;

  if (rank < 0) {
    // ---- clock keeper: dependent-FMA spin until all workers signal done.
    const int lane_ = tid & 63;
    float x = (float)tid + 1.0f;
    unsigned d = 0;
    do {
      #pragma unroll
      for (int i = 0; i < 1024; ++i) x = __builtin_fmaf(x, 1.0000001f, 1.0e-30f);
      asm volatile("" :: "v"(x));                  // keep the chain live (no DCE)
      if (lane_ == 0)
        d = __hip_atomic_fetch_add(&bar[96], 0u, __ATOMIC_RELAXED,
                                   __HIP_MEMORY_SCOPE_AGENT);
      d = __shfl(d, 0);
    } while (d < NWRK);
    return;
  }

  const int wave = tid >> 6, lane = tid & 63;
  const int g   = rank >> 4;                       // batch group 0/1
  const int wgi = rank & 15;                       // index within group
  const int B0  = g * 32;                          // group's batch base
  const int U0  = wgi * 32;                        // WG's unit base
  const int mt2 = wgi * 4 + wave;                  // 0..63 within group
  const int mtA = 2 * mt2, mtB = mtA + 1;          // unit m-tiles 0..127
  const int bl  = lane & 15;                       // local batch (tile 0); +16 tile 1
  const int bA  = B0 + bl;                         // global batch (tile 0)
  const int hi  = lane >> 4;                       // 0..3
  const int koff = hi * 8;
  const int ulA = 8 * wave + hi;                   // unit-local in WG's 32-slice
  const int ulB = ulA + 4;
  const int uA  = U0 + ulA;                        // global unit ids
  const int uB  = U0 + ulB;
  const float4 biasA = *reinterpret_cast<const float4*>(biasp + mtA * 16 + hi * 4);
  const float4 biasB = *reinterpret_cast<const float4*>(biasp + mtB * 16 + hi * 4);

  // preload both weight slices: 2 x 18 k-tiles x 8 bf16/lane = 144 VGPRs
  short8 wA[18], wB[18];
  {
    const u16* wa = wp + (size_t)mtA * (18 * 512) + lane * 8;
    const u16* wb = wp + (size_t)mtB * (18 * 512) + lane * 8;
    #pragma unroll
    for (int kt = 0; kt < 18; ++kt) {
      wA[kt] = *reinterpret_cast<const short8*>(wa + kt * 512);
      wB[kt] = *reinterpret_cast<const short8*>(wb + kt * 512);
    }
  }

  unsigned* grpcnt = &bar[g * 32];                 // per-group counter (own 128B line)
  float cA0 = 0.f, cA1 = 0.f, cB0 = 0.f, cB1 = 0.f;
  f32x4 accA0, accA1, accB0, accB1;

  // LDS fragment-read constants (local rows bl / bl+16; swizzle by row&7)
  const int r0base = bl * 1024;
  const int r1base = r0base + 16 * 1024;
  const int rmask  = (bl & 7) << 4;                // (bl+16)&7 == bl&7
  const int fr_hib = hi * 16;

  // staging constants: rows p*8+strow, col-16B stcol; swizzle=(row&7)<<4=strow<<4
  const int strow = tid >> 5;                      // 0..7
  const int stcol = tid & 31;                      // 16B chunk within 512B half
  const int stswz = strow << 4;

#define XPART(T) do { \
    const u16* xt_ = seq + (size_t)(T) * 4096; \
    short8 x0a = *reinterpret_cast<const short8*>(xt_ + bA * 64 + koff); \
    short8 x1a = *reinterpret_cast<const short8*>(xt_ + (bA + 16) * 64 + koff); \
    short8 x0b = *reinterpret_cast<const short8*>(xt_ + bA * 64 + 32 + koff); \
    short8 x1b = *reinterpret_cast<const short8*>(xt_ + (bA + 16) * 64 + 32 + koff); \
    f32x4 z_ = {0.f, 0.f, 0.f, 0.f}; \
    accA0 = __builtin_amdgcn_mfma_f32_16x16x32_bf16(wA[0], x0a, z_, 0, 0, 0); \
    accA1 = __builtin_amdgcn_mfma_f32_16x16x32_bf16(wA[0], x1a, z_, 0, 0, 0); \
    accB0 = __builtin_amdgcn_mfma_f32_16x16x32_bf16(wB[0], x0a, z_, 0, 0, 0); \
    accB1 = __builtin_amdgcn_mfma_f32_16x16x32_bf16(wB[0], x1a, z_, 0, 0, 0); \
    accA0 = __builtin_amdgcn_mfma_f32_16x16x32_bf16(wA[1], x0b, accA0, 0, 0, 0); \
    accA1 = __builtin_amdgcn_mfma_f32_16x16x32_bf16(wA[1], x1b, accA1, 0, 0, 0); \
    accB0 = __builtin_amdgcn_mfma_f32_16x16x32_bf16(wB[1], x0b, accB0, 0, 0, 0); \
    accB1 = __builtin_amdgcn_mfma_f32_16x16x32_bf16(wB[1], x1b, accB1, 0, 0, 0); \
  } while (0)

  XPART(0);                                        // x-part for t=0 (h(-1)=0)

  for (int t = 0; t < TP; ++t) {
    // ---- wait for own group's h(t-1): ONE RMW per WG per poll iteration
    if (t > 0) {
      if (tid == 0) {
        const unsigned tgt = (unsigned)(16 * t);
        for (;;) {
          unsigned v = __hip_atomic_fetch_add(grpcnt, 0u, __ATOMIC_RELAXED,
                                              __HIP_MEMORY_SCOPE_WORKGROUP);
          if (v >= tgt) break;
          __builtin_amdgcn_s_sleep(1);
        }
      }
      __syncthreads();
    }

    const u16* hc = (t & 1) ? h1buf : h0buf;
    u16* hn = (t & 1) ? h0buf : h1buf;

    // ---- stage the GROUP's 32KB h-half, K-SPLIT: issue all 8 loads, wait only
    // the first-half columns (bytes 0..511 of each row), write+barrier, compute
    // kt 0..7 while the second half's latency hides; then write+barrier, kt 8..15.
    const u16* hsrc = hc + (size_t)B0 * 512;
    f32x4 va[4], vb[4];
    #pragma unroll
    for (int p = 0; p < 4; ++p)
      va[p] = load16_sc0(hsrc + (size_t)(p * 8 + strow) * 512 + stcol * 8);
    #pragma unroll
    for (int p = 0; p < 4; ++p)
      vb[p] = load16_sc0(hsrc + (size_t)(p * 8 + strow) * 512 + 256 + stcol * 8);
    asm volatile("s_waitcnt vmcnt(4)" ::: "memory");
    __builtin_amdgcn_sched_barrier(0);
    #pragma unroll
    for (int p = 0; p < 4; ++p)
      *reinterpret_cast<f32x4*>(hl + (p * 8 + strow) * 1024 +
                                ((stcol * 16) ^ stswz)) = va[p];
    __syncthreads();

    // ---- kt 0..7 (columns 0..511B, region A)
    #pragma unroll
    for (int kt = 0; kt < 8; ++kt) {
      int off = (kt * 64 + fr_hib) ^ rmask;
      short8 b0 = *reinterpret_cast<const short8*>(hl + r0base + off);
      short8 b1 = *reinterpret_cast<const short8*>(hl + r1base + off);
      accA0 = __builtin_amdgcn_mfma_f32_16x16x32_bf16(wA[kt + 2], b0, accA0, 0, 0, 0);
      accA1 = __builtin_amdgcn_mfma_f32_16x16x32_bf16(wA[kt + 2], b1, accA1, 0, 0, 0);
      accB0 = __builtin_amdgcn_mfma_f32_16x16x32_bf16(wB[kt + 2], b0, accB0, 0, 0, 0);
      accB1 = __builtin_amdgcn_mfma_f32_16x16x32_bf16(wB[kt + 2], b1, accB1, 0, 0, 0);
    }

    // ---- write second half (long arrived), barrier, kt 8..15 (region B)
    asm volatile("s_waitcnt vmcnt(0)" ::: "memory");
    __builtin_amdgcn_sched_barrier(0);
    #pragma unroll
    for (int p = 0; p < 4; ++p)
      *reinterpret_cast<f32x4*>(hl + (p * 8 + strow) * 1024 + 512 +
                                ((stcol * 16) ^ stswz)) = vb[p];
    __syncthreads();
    #pragma unroll
    for (int kt = 8; kt < 16; ++kt) {
      int off = (kt * 64 + fr_hib) ^ rmask;
      short8 b0 = *reinterpret_cast<const short8*>(hl + r0base + off);
      short8 b1 = *reinterpret_cast<const short8*>(hl + r1base + off);
      accA0 = __builtin_amdgcn_mfma_f32_16x16x32_bf16(wA[kt + 2], b0, accA0, 0, 0, 0);
      accA1 = __builtin_amdgcn_mfma_f32_16x16x32_bf16(wA[kt + 2], b1, accA1, 0, 0, 0);
      accB0 = __builtin_amdgcn_mfma_f32_16x16x32_bf16(wB[kt + 2], b0, accB0, 0, 0, 0);
      accB1 = __builtin_amdgcn_mfma_f32_16x16x32_bf16(wB[kt + 2], b1, accB1, 0, 0, 0);
    }

    // ---- gates (i,f,g,o in acc[0..3] of each lane, per mt x batch-tile)
    float iA0 = sigmoidf_(accA0[0] + biasA.x);
    float fA0 = sigmoidf_(accA0[1] + biasA.y);
    float gA0 = tanhf_(accA0[2] + biasA.z);
    float oA0 = sigmoidf_(accA0[3] + biasA.w);
    cA0 = fA0 * cA0 + iA0 * gA0;
    float hvA0 = oA0 * tanhf_(cA0);
    float iA1 = sigmoidf_(accA1[0] + biasA.x);
    float fA1 = sigmoidf_(accA1[1] + biasA.y);
    float gA1 = tanhf_(accA1[2] + biasA.z);
    float oA1 = sigmoidf_(accA1[3] + biasA.w);
    cA1 = fA1 * cA1 + iA1 * gA1;
    float hvA1 = oA1 * tanhf_(cA1);
    float iB0 = sigmoidf_(accB0[0] + biasB.x);
    float fB0 = sigmoidf_(accB0[1] + biasB.y);
    float gB0 = tanhf_(accB0[2] + biasB.z);
    float oB0 = sigmoidf_(accB0[3] + biasB.w);
    cB0 = fB0 * cB0 + iB0 * gB0;
    float hvB0 = oB0 * tanhf_(cB0);
    float iB1 = sigmoidf_(accB1[0] + biasB.x);
    float fB1 = sigmoidf_(accB1[1] + biasB.y);
    float gB1 = tanhf_(accB1[2] + biasB.z);
    float oB1 = sigmoidf_(accB1[3] + biasB.w);
    cB1 = fB1 * cB1 + iB1 * gB1;
    float hvB1 = oB1 * tanhf_(cB1);

    // ---- stage h slice (32 batches x 32 units) in padded LDS
    ostage[bl][ulA]      = f2bf(hvA0);
    ostage[bl + 16][ulA] = f2bf(hvA1);
    ostage[bl][ulB]      = f2bf(hvB0);
    ostage[bl + 16][ulB] = f2bf(hvB1);
    if (t == TP - 1) {
      hfin[bA * 512 + uA]        = hvA0;
      hfin[(bA + 16) * 512 + uA] = hvA1;
      hfin[bA * 512 + uB]        = hvB0;
      hfin[(bA + 16) * 512 + uB] = hvB1;
    }
    __syncthreads();

    // ---- coalesced sc0 h stores: 128 threads x 16B into XCD L2
    if (tid < 128) {
      int b_l = tid >> 2, q = tid & 3;
      f32x4 val = *reinterpret_cast<const f32x4*>(&ostage[b_l][q * 8]);
      store16_sc0(hn + (size_t)(B0 + b_l) * 512 + U0 + q * 8, val);
    }
    asm volatile("s_waitcnt vmcnt(0)" ::: "memory");
    __syncthreads();                               // all waves' stores drained

    // ---- signal own group: ONE atomic RMW per WG
    if (tid == 0)
      __hip_atomic_fetch_add(grpcnt, 1u, __ATOMIC_RELAXED, __HIP_MEMORY_SCOPE_WORKGROUP);

    // ---- x-part prefetch for t+1 (plain cached loads) overlaps others' polls
    if (t + 1 < TP) XPART(t + 1);
  }
#undef XPART

  // ---- tell the clock keepers we're done (MALL-scope RMW, cross-XCD visible)
  if (tid == 0)
    __hip_atomic_fetch_add(&bar[96], 1u, __ATOMIC_RELAXED, __HIP_MEMORY_SCOPE_AGENT);
}

// ---- final linear: out[b][o] = h . lin_w[o] + lin_b[o]  (fp32, float4 reads)
__global__ void k_fc(const float* __restrict__ hfin, const float* __restrict__ lin_w,
                     const float* __restrict__ lin_b, float* __restrict__ out) {
  int b = blockIdx.x, o = threadIdx.x;             // 128 threads
  const float4* hp = reinterpret_cast<const float4*>(hfin + b * 512);
  const float4* wq = reinterpret_cast<const float4*>(lin_w + o * 512);
  float s = lin_b[o];
  #pragma unroll 8
  for (int j = 0; j < 128; ++j) {
    float4 h4 = hp[j], w4 = wq[j];
    s += h4.x * w4.x + h4.y * w4.y + h4.z * w4.z + h4.w * w4.w;
  }
  out[b * 128 + o] = s;
}

extern "C" void kernel_launch(void* const* d_in, const int* in_sizes, int n_in,
                              void* d_out, int out_size, void* d_ws, size_t ws_size,
                              hipStream_t stream) {
  const float* inX    = (const float*)d_in[0];
  const float* conv_w = (const float*)d_in[2];
  const float* conv_b = (const float*)d_in[3];
  const float* w_ih   = (const float*)d_in[4];
  const float* w_hh   = (const float*)d_in[5];
  const float* b_ih   = (const float*)d_in[6];
  const float* b_hh   = (const float*)d_in[7];
  const float* lin_w  = (const float*)d_in[8];
  const float* lin_b  = (const float*)d_in[9];
  float* out = (float*)d_out;
  char* ws = (char*)d_ws;
  u16*      wpack = (u16*)(ws + OFF_WPACK);
  u16*      seq   = (u16*)(ws + OFF_SEQ);
  float*    biasp = (float*)(ws + OFF_BIAS);
  u16*      h0b   = (u16*)(ws + OFF_H0);
  u16*      h1b   = (u16*)(ws + OFF_H1);
  float*    hfin  = (float*)(ws + OFF_HFIN);
  unsigned* bar   = (unsigned*)(ws + OFF_BAR);
  float*    cwT   = (float*)(ws + OFF_CWT);

  k_init<<<dim3(128), dim3(256), 0, stream>>>(b_ih, b_hh, biasp, (unsigned*)(ws + OFF_H0), bar);
  k_pack<<<dim3(4608), dim3(256), 0, stream>>>(w_ih, w_hh, wpack);
  k_packc<<<dim3(96), dim3(256), 0, stream>>>(conv_w, cwT);
  k_conv<<<dim3(256, 64), dim3(256), 0, stream>>>(inX, cwT, conv_b, seq);
  k_lstm<<<dim3(256), dim3(256), 0, stream>>>(seq, wpack, biasp, h0b, h1b, hfin, bar);
  k_fc<<<dim3(64), dim3(128), 0, stream>>>(hfin, lin_w, lin_b, out);
}

// Round 17
// 3321.634 us; speedup vs baseline: 1.1879x; 1.0412x over previous
//
#include <hip/hip_runtime.h>

typedef __attribute__((ext_vector_type(8))) short short8;
typedef __attribute__((ext_vector_type(4))) float f32x4;
typedef unsigned short u16;
typedef unsigned long long u64;

#define TP   1022      // conv output length = T-2
#define NWRK 32        // worker WGs (one XCD): 2 batch-groups x 16

// ws layout (byte offsets, all 256-aligned)
#define OFF_WPACK   0            // 2048*576*2   = 2359296
#define OFF_SEQ     2359296      // 1022*64*64*2 = 8372224
#define OFF_BIAS    10993664     // 2048*4      = 8192
#define OFF_H0      11001856     // 64*512*2     = 65536
#define OFF_H1      11067392     // 64*512*2     = 65536
#define OFF_HFIN    11132928     // 64*512*4     = 131072
#define OFF_BAR     11264000
// bar u32 idx: grp0 cnt @0 | xcdcnt @8..15 | designated @16 | grp1 cnt @32 |
//              keeper-done @96   (separate 128B lines)
#define OFF_CWT     11266048     // transposed conv weights: 384*64*4 = 98304

__device__ inline u16 f2bf(float x) {
  union { float f; unsigned u; } un; un.f = x;
  unsigned r = un.u + 0x7fffu + ((un.u >> 16) & 1u);  // RNE
  return (u16)(r >> 16);
}
__device__ inline float sigmoidf_(float x) { return 1.f / (1.f + __expf(-x)); }
__device__ inline float tanhf_(float x)    { return 2.f / (1.f + __expf(-2.f * x)) - 1.f; }

// 16B load/store served by the XCD-local L2 (sc0 bypasses L1 — required because
// h lines are re-read every 2 steps and would otherwise hit stale L1 data).
__device__ inline f32x4 load16_sc0(const void* p) {
  f32x4 r;
  asm volatile("global_load_dwordx4 %0, %1, off sc0" : "=v"(r) : "v"(p) : "memory");
  return r;
}
__device__ inline void store16_sc0(void* p, f32x4 v) {
  asm volatile("global_store_dwordx4 %0, %1, off sc0" :: "v"(p), "v"(v) : "memory");
}

// ---- init: zero h buffers + barrier region, packed bias, transposed conv weights
__global__ void k_init(const float* __restrict__ b_ih, const float* __restrict__ b_hh,
                       const float* __restrict__ conv_w,
                       float* __restrict__ biasp, unsigned* __restrict__ hzero,
                       unsigned* __restrict__ bar, float* __restrict__ cwT) {
  int tid = blockIdx.x * 256 + threadIdx.x;
  if (tid < 32768) hzero[tid] = 0u;                 // both h bufs (131072 B)
  if (tid < 2048) {
    int j = tid >> 2, g = tid & 3;
    int row = g * 512 + j;
    biasp[tid] = b_ih[row] + b_hh[row];
  }
  if (tid < 128) bar[tid] = 0u;                     // counters + xcdcnt + designated + done
  if (tid < 24576) {                                // cwT[(i*3+k)*64 + oc]
    int ik = tid >> 6, oc = tid & 63;
    cwT[ik * 64 + oc] = conv_w[oc * 384 + ik];
  }
}

// ---- pack W = [w_ih ; w_hh] (2048 x 576) into MFMA A-fragment order, bf16.
__global__ void k_pack(const float* __restrict__ w_ih, const float* __restrict__ w_hh,
                       u16* __restrict__ wp) {
  int idx = blockIdx.x * 256 + threadIdx.x;        // < 128*18*512 = 1179648
  int nt = idx / 9216;
  int rem = idx - nt * 9216;
  int kt = rem / 512;
  int rem2 = rem - kt * 512;
  int lane = rem2 >> 3, i = rem2 & 7;
  int n = nt * 16 + (lane & 15);
  int k = kt * 32 + (lane >> 4) * 8 + i;
  int j = n >> 2, g = n & 3;
  int row = g * 512 + j;
  float v = (k < 64) ? w_ih[row * 64 + k] : w_hh[row * 512 + (k - 64)];
  wp[idx] = f2bf(v);
}

// ---- normalize (fused) + conv1d(k=3, VALID) + relu -> seq[t][b][oc] bf16.
// Loop-inverted: lane = t (64 t per chunk), wave = 16-oc slice; weights go
// through the SCALAR path (oc0 readfirstlane'd -> s_load broadcasts, K$-hot);
// x values from bank-swizzled LDS transpose buffer (i ^ (t&31), conflict-free
// on the hot read). Per-k norm factors hoisted out of the MAC loop.
__global__ __launch_bounds__(256) void k_conv(const float* __restrict__ inX,
                                              const float* __restrict__ cwT,
                                              const float* __restrict__ conv_b,
                                              u16* __restrict__ seq) {
  __shared__ float xs[66 * 128];                   // raw x rows, swizzled
  __shared__ float rn[66];
  __shared__ u16 outb[64 * 64];                    // [t_local][oc]
  const int tid = threadIdx.x;
  const int b = blockIdx.x >> 2;
  const int q = blockIdx.x & 3;
  const int wave = tid >> 6;
  const int oc0 = __builtin_amdgcn_readfirstlane(wave * 16);
  const int tl = tid & 63;                         // lane = local t
  const float4 bias4a = *reinterpret_cast<const float4*>(conv_b + oc0);
  const float4 bias4b = *reinterpret_cast<const float4*>(conv_b + oc0 + 4);
  const float4 bias4c = *reinterpret_cast<const float4*>(conv_b + oc0 + 8);
  const float4 bias4d = *reinterpret_cast<const float4*>(conv_b + oc0 + 12);

  for (int c = 0; c < 4; ++c) {
    const int t0 = (q * 4 + c) * 64;
    // ---- stage 66 rows (raw), swizzled: bank = (i ^ (row&31)) % 32
    for (int e = tid; e < 66 * 128; e += 256) {
      int tt = e >> 7, i = e & 127;
      int gt = t0 + tt;
      float v = (gt < 1024) ? inX[((size_t)b * 1024 + gt) * 128 + i] : 0.f;
      xs[tt * 128 + (i ^ (tt & 31))] = v;
    }
    __syncthreads();
    // ---- row norms (32-lane groups)
    {
      int g32 = tid >> 5, l32 = tid & 31;
      for (int r = g32; r < 66; r += 8) {
        float s = 0.f;
        #pragma unroll
        for (int jj = 0; jj < 4; ++jj) {
          float v = xs[r * 128 + ((l32 * 4 + jj) ^ (r & 31))];
          s += v * v;
        }
        #pragma unroll
        for (int d = 1; d < 32; d <<= 1) s += __shfl_xor(s, d, 32);
        if (l32 == 0) rn[r] = 1.f / fmaxf(sqrtf(s), 1e-12f);
      }
    }
    __syncthreads();
    // ---- conv: each lane = one t, 16 oc accumulators, weights via s_load
    {
      float acc[16];
      #pragma unroll
      for (int j = 0; j < 16; ++j) acc[j] = 0.f;
      const float rn0 = rn[tl], rn1 = rn[tl + 1], rn2 = rn[tl + 2];
      const int a0 = (tl + 0) * 128, m0 = (tl + 0) & 31;
      const int a1 = (tl + 1) * 128, m1 = (tl + 1) & 31;
      const int a2 = (tl + 2) * 128, m2 = (tl + 2) & 31;
      for (int i = 0; i < 128; ++i) {
        float x0 = xs[a0 + (i ^ m0)] * rn0;
        float x1 = xs[a1 + (i ^ m1)] * rn1;
        float x2 = xs[a2 + (i ^ m2)] * rn2;
        const float* w0 = cwT + (i * 3 + 0) * 64 + oc0;
        const float* w1 = cwT + (i * 3 + 1) * 64 + oc0;
        const float* w2 = cwT + (i * 3 + 2) * 64 + oc0;
        #pragma unroll
        for (int j = 0; j < 16; ++j)
          acc[j] += w0[j] * x0 + w1[j] * x1 + w2[j] * x2;
      }
      const float bj[16] = {bias4a.x, bias4a.y, bias4a.z, bias4a.w,
                            bias4b.x, bias4b.y, bias4b.z, bias4b.w,
                            bias4c.x, bias4c.y, bias4c.z, bias4c.w,
                            bias4d.x, bias4d.y, bias4d.z, bias4d.w};
      #pragma unroll
      for (int j = 0; j < 16; ++j)
        outb[tl * 64 + oc0 + j] = f2bf(fmaxf(acc[j] + bj[j], 0.f));
    }
    __syncthreads();
    // ---- coalesced store: seq[t][b][oc]
    for (int e = tid; e < 4096; e += 256) {
      int tt = e >> 6, oc = e & 63;
      int gt = t0 + tt;
      if (gt < TP) seq[((size_t)gt * 64 + b) * 64 + oc] = outb[tt * 64 + oc];
    }
    __syncthreads();
  }
}

// ---- persistent LSTM on ONE XCD, 2 independent batch-groups of 16 WGs.
// BYTE-IDENTICAL to the round-14/16 passing kernel. Five attempts to improve
// it (volume/degree/overlap/barrier rewrites) gave 2 neutrals + 3 deadlocks —
// this structure is the proven floor for this topology.
__global__ __launch_bounds__(256, 1) void k_lstm(const u16* __restrict__ seq,
                                                 const u16* __restrict__ wp,
                                                 const float* __restrict__ biasp,
                                                 u16* h0buf, u16* h1buf,
                                                 float* __restrict__ hfin,
                                                 unsigned* bar) {
  const int tid = threadIdx.x;
  __shared__ int s_rank;
  __shared__ __align__(16) char hl[32768];         // staged group h-half, swizzled
  __shared__ u16 ostage[32][40];                   // [batch_local][unit_local], padded

  // ---- XCD self-designation (setup only; agent-scope atomics via MALL)
  if (tid == 0) {
    unsigned xcd;
    asm volatile("s_getreg_b32 %0, hwreg(HW_REG_XCC_ID)" : "=s"(xcd));
    xcd &= 7u;
    unsigned r = __hip_atomic_fetch_add(&bar[8 + xcd], 1u, __ATOMIC_RELAXED,
                                        __HIP_MEMORY_SCOPE_AGENT);
    if (r == NWRK - 1) {
      unsigned expected = 0u;
      __hip_atomic_compare_exchange_strong(&bar[16], &expected, xcd + 1u,
                                           __ATOMIC_RELAXED, __ATOMIC_RELAXED,
                                           __HIP_MEMORY_SCOPE_AGENT);
    }
    unsigned d;
    while ((d = __hip_atomic_load(&bar[16], __ATOMIC_RELAXED,
                                  __HIP_MEMORY_SCOPE_AGENT)) == 0u)
      __builtin_amdgcn_s_sleep(8);
    s_rank = (xcd == d - 1u && r < NWRK) ? (int)r : -1;
  }
  __syncthreads();
  const int rank = s_rank;

  if (rank < 0) {
    // ---- clock keeper: dependent-FMA spin until all workers signal done.
    const int lane_ = tid & 63;
    float x = (float)tid + 1.0f;
    unsigned d = 0;
    do {
      #pragma unroll
      for (int i = 0; i < 1024; ++i) x = __builtin_fmaf(x, 1.0000001f, 1.0e-30f);
      asm volatile("" :: "v"(x));                  // keep the chain live (no DCE)
      if (lane_ == 0)
        d = __hip_atomic_fetch_add(&bar[96], 0u, __ATOMIC_RELAXED,
                                   __HIP_MEMORY_SCOPE_AGENT);
      d = __shfl(d, 0);
    } while (d < NWRK);
    return;
  }

  const int wave = tid >> 6, lane = tid & 63;
  const int g   = rank >> 4;                       // batch group 0/1
  const int wgi = rank & 15;                       // index within group
  const int B0  = g * 32;                          // group's batch base
  const int U0  = wgi * 32;                        // WG's unit base
  const int mt2 = wgi * 4 + wave;                  // 0..63 within group
  const int mtA = 2 * mt2, mtB = mtA + 1;          // unit m-tiles 0..127
  const int bl  = lane & 15;                       // local batch (tile 0); +16 tile 1
  const int bA  = B0 + bl;                         // global batch (tile 0)
  const int hi  = lane >> 4;                       // 0..3
  const int koff = hi * 8;
  const int ulA = 8 * wave + hi;                   // unit-local in WG's 32-slice
  const int ulB = ulA + 4;
  const int uA  = U0 + ulA;                        // global unit ids
  const int uB  = U0 + ulB;
  const float4 biasA = *reinterpret_cast<const float4*>(biasp + mtA * 16 + hi * 4);
  const float4 biasB = *reinterpret_cast<const float4*>(biasp + mtB * 16 + hi * 4);

  // preload both weight slices: 2 x 18 k-tiles x 8 bf16/lane = 144 VGPRs
  short8 wA[18], wB[18];
  {
    const u16* wa = wp + (size_t)mtA * (18 * 512) + lane * 8;
    const u16* wb = wp + (size_t)mtB * (18 * 512) + lane * 8;
    #pragma unroll
    for (int kt = 0; kt < 18; ++kt) {
      wA[kt] = *reinterpret_cast<const short8*>(wa + kt * 512);
      wB[kt] = *reinterpret_cast<const short8*>(wb + kt * 512);
    }
  }

  unsigned* grpcnt = &bar[g * 32];                 // per-group counter (own 128B line)
  float cA0 = 0.f, cA1 = 0.f, cB0 = 0.f, cB1 = 0.f;
  f32x4 accA0, accA1, accB0, accB1;

  // LDS fragment-read constants (local rows bl / bl+16; swizzle by row&7)
  const int r0base = bl * 1024;
  const int r1base = r0base + 16 * 1024;
  const int rmask  = (bl & 7) << 4;                // (bl+16)&7 == bl&7
  const int fr_hib = hi * 16;

  // staging constants: rows p*8+strow, col-16B stcol; swizzle=(row&7)<<4=strow<<4
  const int strow = tid >> 5;                      // 0..7
  const int stcol = tid & 31;                      // 16B chunk within 512B half
  const int stswz = strow << 4;

#define XPART(T) do { \
    const u16* xt_ = seq + (size_t)(T) * 4096; \
    short8 x0a = *reinterpret_cast<const short8*>(xt_ + bA * 64 + koff); \
    short8 x1a = *reinterpret_cast<const short8*>(xt_ + (bA + 16) * 64 + koff); \
    short8 x0b = *reinterpret_cast<const short8*>(xt_ + bA * 64 + 32 + koff); \
    short8 x1b = *reinterpret_cast<const short8*>(xt_ + (bA + 16) * 64 + 32 + koff); \
    f32x4 z_ = {0.f, 0.f, 0.f, 0.f}; \
    accA0 = __builtin_amdgcn_mfma_f32_16x16x32_bf16(wA[0], x0a, z_, 0, 0, 0); \
    accA1 = __builtin_amdgcn_mfma_f32_16x16x32_bf16(wA[0], x1a, z_, 0, 0, 0); \
    accB0 = __builtin_amdgcn_mfma_f32_16x16x32_bf16(wB[0], x0a, z_, 0, 0, 0); \
    accB1 = __builtin_amdgcn_mfma_f32_16x16x32_bf16(wB[0], x1a, z_, 0, 0, 0); \
    accA0 = __builtin_amdgcn_mfma_f32_16x16x32_bf16(wA[1], x0b, accA0, 0, 0, 0); \
    accA1 = __builtin_amdgcn_mfma_f32_16x16x32_bf16(wA[1], x1b, accA1, 0, 0, 0); \
    accB0 = __builtin_amdgcn_mfma_f32_16x16x32_bf16(wB[1], x0b, accB0, 0, 0, 0); \
    accB1 = __builtin_amdgcn_mfma_f32_16x16x32_bf16(wB[1], x1b, accB1, 0, 0, 0); \
  } while (0)

  XPART(0);                                        // x-part for t=0 (h(-1)=0)

  for (int t = 0; t < TP; ++t) {
    // ---- wait for own group's h(t-1): ONE RMW per WG per poll iteration
    if (t > 0) {
      if (tid == 0) {
        const unsigned tgt = (unsigned)(16 * t);
        for (;;) {
          unsigned v = __hip_atomic_fetch_add(grpcnt, 0u, __ATOMIC_RELAXED,
                                              __HIP_MEMORY_SCOPE_WORKGROUP);
          if (v >= tgt) break;
          __builtin_amdgcn_s_sleep(1);
        }
      }
      __syncthreads();
    }

    const u16* hc = (t & 1) ? h1buf : h0buf;
    u16* hn = (t & 1) ? h0buf : h1buf;

    // ---- stage the GROUP's 32KB h-half, K-SPLIT: issue all 8 loads, wait only
    // the first-half columns (bytes 0..511 of each row), write+barrier, compute
    // kt 0..7 while the second half's latency hides; then write+barrier, kt 8..15.
    const u16* hsrc = hc + (size_t)B0 * 512;
    f32x4 va[4], vb[4];
    #pragma unroll
    for (int p = 0; p < 4; ++p)
      va[p] = load16_sc0(hsrc + (size_t)(p * 8 + strow) * 512 + stcol * 8);
    #pragma unroll
    for (int p = 0; p < 4; ++p)
      vb[p] = load16_sc0(hsrc + (size_t)(p * 8 + strow) * 512 + 256 + stcol * 8);
    asm volatile("s_waitcnt vmcnt(4)" ::: "memory");
    __builtin_amdgcn_sched_barrier(0);
    #pragma unroll
    for (int p = 0; p < 4; ++p)
      *reinterpret_cast<f32x4*>(hl + (p * 8 + strow) * 1024 +
                                ((stcol * 16) ^ stswz)) = va[p];
    __syncthreads();

    // ---- kt 0..7 (columns 0..511B, region A)
    #pragma unroll
    for (int kt = 0; kt < 8; ++kt) {
      int off = (kt * 64 + fr_hib) ^ rmask;
      short8 b0 = *reinterpret_cast<const short8*>(hl + r0base + off);
      short8 b1 = *reinterpret_cast<const short8*>(hl + r1base + off);
      accA0 = __builtin_amdgcn_mfma_f32_16x16x32_bf16(wA[kt + 2], b0, accA0, 0, 0, 0);
      accA1 = __builtin_amdgcn_mfma_f32_16x16x32_bf16(wA[kt + 2], b1, accA1, 0, 0, 0);
      accB0 = __builtin_amdgcn_mfma_f32_16x16x32_bf16(wB[kt + 2], b0, accB0, 0, 0, 0);
      accB1 = __builtin_amdgcn_mfma_f32_16x16x32_bf16(wB[kt + 2], b1, accB1, 0, 0, 0);
    }

    // ---- write second half (long arrived), barrier, kt 8..15 (region B)
    asm volatile("s_waitcnt vmcnt(0)" ::: "memory");
    __builtin_amdgcn_sched_barrier(0);
    #pragma unroll
    for (int p = 0; p < 4; ++p)
      *reinterpret_cast<f32x4*>(hl + (p * 8 + strow) * 1024 + 512 +
                                ((stcol * 16) ^ stswz)) = vb[p];
    __syncthreads();
    #pragma unroll
    for (int kt = 8; kt < 16; ++kt) {
      int off = (kt * 64 + fr_hib) ^ rmask;
      short8 b0 = *reinterpret_cast<const short8*>(hl + r0base + off);
      short8 b1 = *reinterpret_cast<const short8*>(hl + r1base + off);
      accA0 = __builtin_amdgcn_mfma_f32_16x16x32_bf16(wA[kt + 2], b0, accA0, 0, 0, 0);
      accA1 = __builtin_amdgcn_mfma_f32_16x16x32_bf16(wA[kt + 2], b1, accA1, 0, 0, 0);
      accB0 = __builtin_amdgcn_mfma_f32_16x16x32_bf16(wB[kt + 2], b0, accB0, 0, 0, 0);
      accB1 = __builtin_amdgcn_mfma_f32_16x16x32_bf16(wB[kt + 2], b1, accB1, 0, 0, 0);
    }

    // ---- gates (i,f,g,o in acc[0..3] of each lane, per mt x batch-tile)
    float iA0 = sigmoidf_(accA0[0] + biasA.x);
    float fA0 = sigmoidf_(accA0[1] + biasA.y);
    float gA0 = tanhf_(accA0[2] + biasA.z);
    float oA0 = sigmoidf_(accA0[3] + biasA.w);
    cA0 = fA0 * cA0 + iA0 * gA0;
    float hvA0 = oA0 * tanhf_(cA0);
    float iA1 = sigmoidf_(accA1[0] + biasA.x);
    float fA1 = sigmoidf_(accA1[1] + biasA.y);
    float gA1 = tanhf_(accA1[2] + biasA.z);
    float oA1 = sigmoidf_(accA1[3] + biasA.w);
    cA1 = fA1 * cA1 + iA1 * gA1;
    float hvA1 = oA1 * tanhf_(cA1);
    float iB0 = sigmoidf_(accB0[0] + biasB.x);
    float fB0 = sigmoidf_(accB0[1] + biasB.y);
    float gB0 = tanhf_(accB0[2] + biasB.z);
    float oB0 = sigmoidf_(accB0[3] + biasB.w);
    cB0 = fB0 * cB0 + iB0 * gB0;
    float hvB0 = oB0 * tanhf_(cB0);
    float iB1 = sigmoidf_(accB1[0] + biasB.x);
    float fB1 = sigmoidf_(accB1[1] + biasB.y);
    float gB1 = tanhf_(accB1[2] + biasB.z);
    float oB1 = sigmoidf_(accB1[3] + biasB.w);
    cB1 = fB1 * cB1 + iB1 * gB1;
    float hvB1 = oB1 * tanhf_(cB1);

    // ---- stage h slice (32 batches x 32 units) in padded LDS
    ostage[bl][ulA]      = f2bf(hvA0);
    ostage[bl + 16][ulA] = f2bf(hvA1);
    ostage[bl][ulB]      = f2bf(hvB0);
    ostage[bl + 16][ulB] = f2bf(hvB1);
    if (t == TP - 1) {
      hfin[bA * 512 + uA]        = hvA0;
      hfin[(bA + 16) * 512 + uA] = hvA1;
      hfin[bA * 512 + uB]        = hvB0;
      hfin[(bA + 16) * 512 + uB] = hvB1;
    }
    __syncthreads();

    // ---- coalesced sc0 h stores: 128 threads x 16B into XCD L2
    if (tid < 128) {
      int b_l = tid >> 2, q = tid & 3;
      f32x4 val = *reinterpret_cast<const f32x4*>(&ostage[b_l][q * 8]);
      store16_sc0(hn + (size_t)(B0 + b_l) * 512 + U0 + q * 8, val);
    }
    asm volatile("s_waitcnt vmcnt(0)" ::: "memory");
    __syncthreads();                               // all waves' stores drained

    // ---- signal own group: ONE atomic RMW per WG
    if (tid == 0)
      __hip_atomic_fetch_add(grpcnt, 1u, __ATOMIC_RELAXED, __HIP_MEMORY_SCOPE_WORKGROUP);

    // ---- x-part prefetch for t+1 (plain cached loads) overlaps others' polls
    if (t + 1 < TP) XPART(t + 1);
  }
#undef XPART

  // ---- tell the clock keepers we're done (MALL-scope RMW, cross-XCD visible)
  if (tid == 0)
    __hip_atomic_fetch_add(&bar[96], 1u, __ATOMIC_RELAXED, __HIP_MEMORY_SCOPE_AGENT);
}

// ---- final linear: out[b][o] = h . lin_w[o] + lin_b[o]  (fp32, float4 reads)
__global__ void k_fc(const float* __restrict__ hfin, const float* __restrict__ lin_w,
                     const float* __restrict__ lin_b, float* __restrict__ out) {
  int b = blockIdx.x, o = threadIdx.x;             // 128 threads
  const float4* hp = reinterpret_cast<const float4*>(hfin + b * 512);
  const float4* wq = reinterpret_cast<const float4*>(lin_w + o * 512);
  float s = lin_b[o];
  #pragma unroll 8
  for (int j = 0; j < 128; ++j) {
    float4 h4 = hp[j], w4 = wq[j];
    s += h4.x * w4.x + h4.y * w4.y + h4.z * w4.z + h4.w * w4.w;
  }
  out[b * 128 + o] = s;
}

extern "C" void kernel_launch(void* const* d_in, const int* in_sizes, int n_in,
                              void* d_out, int out_size, void* d_ws, size_t ws_size,
                              hipStream_t stream) {
  const float* inX    = (const float*)d_in[0];
  const float* conv_w = (const float*)d_in[2];
  const float* conv_b = (const float*)d_in[3];
  const float* w_ih   = (const float*)d_in[4];
  const float* w_hh   = (const float*)d_in[5];
  const float* b_ih   = (const float*)d_in[6];
  const float* b_hh   = (const float*)d_in[7];
  const float* lin_w  = (const float*)d_in[8];
  const float* lin_b  = (const float*)d_in[9];
  float* out = (float*)d_out;
  char* ws = (char*)d_ws;
  u16*      wpack = (u16*)(ws + OFF_WPACK);
  u16*      seq   = (u16*)(ws + OFF_SEQ);
  float*    biasp = (float*)(ws + OFF_BIAS);
  u16*      h0b   = (u16*)(ws + OFF_H0);
  u16*      h1b   = (u16*)(ws + OFF_H1);
  float*    hfin  = (float*)(ws + OFF_HFIN);
  unsigned* bar   = (unsigned*)(ws + OFF_BAR);
  float*    cwT   = (float*)(ws + OFF_CWT);

  k_init<<<dim3(128), dim3(256), 0, stream>>>(b_ih, b_hh, conv_w, biasp,
                                              (unsigned*)(ws + OFF_H0), bar, cwT);
  k_pack<<<dim3(4608), dim3(256), 0, stream>>>(w_ih, w_hh, wpack);
  k_conv<<<dim3(256), dim3(256), 0, stream>>>(inX, cwT, conv_b, seq);
  k_lstm<<<dim3(256), dim3(256), 0, stream>>>(seq, wpack, biasp, h0b, h1b, hfin, bar);
  k_fc<<<dim3(64), dim3(128), 0, stream>>>(hfin, lin_w, lin_b, out);
}

// Round 18
// 3308.483 us; speedup vs baseline: 1.1926x; 1.0040x over previous
//
#include <hip/hip_runtime.h>

typedef __attribute__((ext_vector_type(8))) short short8;
typedef __attribute__((ext_vector_type(4))) float f32x4;
typedef unsigned short u16;
typedef unsigned long long u64;

#define TP   1022      // conv output length = T-2
#define NWRK 32        // worker WGs (one XCD): 2 batch-groups x 16

// ws layout (byte offsets, all 256-aligned)
#define OFF_WPACK   0            // 2048*576*2   = 2359296
#define OFF_SEQ     2359296      // 1022*64*64*2 = 8372224
#define OFF_BIAS    10993664     // 2048*4      = 8192
#define OFF_H0      11001856     // 64*512*2     = 65536
#define OFF_H1      11067392     // 64*512*2     = 65536
#define OFF_HFIN    11132928     // 64*512*4     = 131072
#define OFF_BAR     11264000
// bar u32 idx: grp0 cnt @0 | xcdcnt @8..15 | designated @16 | grp1 cnt @32 |
//              keeper-done @96   (separate 128B lines)
#define OFF_CWT     11266048     // transposed conv weights: 384*64*4 = 98304

__device__ inline u16 f2bf(float x) {
  union { float f; unsigned u; } un; un.f = x;
  unsigned r = un.u + 0x7fffu + ((un.u >> 16) & 1u);  // RNE
  return (u16)(r >> 16);
}
__device__ inline float sigmoidf_(float x) { return 1.f / (1.f + __expf(-x)); }
__device__ inline float tanhf_(float x)    { return 2.f / (1.f + __expf(-2.f * x)) - 1.f; }

// 16B load/store served by the XCD-local L2 (sc0 bypasses L1 — required because
// h lines are re-read every 2 steps and would otherwise hit stale L1 data).
__device__ inline f32x4 load16_sc0(const void* p) {
  f32x4 r;
  asm volatile("global_load_dwordx4 %0, %1, off sc0" : "=v"(r) : "v"(p) : "memory");
  return r;
}
__device__ inline void store16_sc0(void* p, f32x4 v) {
  asm volatile("global_store_dwordx4 %0, %1, off sc0" :: "v"(p), "v"(v) : "memory");
}

// ---- init: zero h buffers + barrier region, packed bias, transposed conv weights
__global__ void k_init(const float* __restrict__ b_ih, const float* __restrict__ b_hh,
                       const float* __restrict__ conv_w,
                       float* __restrict__ biasp, unsigned* __restrict__ hzero,
                       unsigned* __restrict__ bar, float* __restrict__ cwT) {
  int tid = blockIdx.x * 256 + threadIdx.x;
  if (tid < 32768) hzero[tid] = 0u;                 // both h bufs (131072 B)
  if (tid < 2048) {
    int j = tid >> 2, g = tid & 3;
    int row = g * 512 + j;
    biasp[tid] = b_ih[row] + b_hh[row];
  }
  if (tid < 128) bar[tid] = 0u;                     // counters + xcdcnt + designated + done
  if (tid < 24576) {                                // cwT[(i*3+k)*64 + oc]
    int ik = tid >> 6, oc = tid & 63;
    cwT[ik * 64 + oc] = conv_w[oc * 384 + ik];
  }
}

// ---- pack W = [w_ih ; w_hh] (2048 x 576) into MFMA A-fragment order, bf16.
__global__ void k_pack(const float* __restrict__ w_ih, const float* __restrict__ w_hh,
                       u16* __restrict__ wp) {
  int idx = blockIdx.x * 256 + threadIdx.x;        // < 128*18*512 = 1179648
  int nt = idx / 9216;
  int rem = idx - nt * 9216;
  int kt = rem / 512;
  int rem2 = rem - kt * 512;
  int lane = rem2 >> 3, i = rem2 & 7;
  int n = nt * 16 + (lane & 15);
  int k = kt * 32 + (lane >> 4) * 8 + i;
  int j = n >> 2, g = n & 3;
  int row = g * 512 + j;
  float v = (k < 64) ? w_ih[row * 64 + k] : w_hh[row * 512 + (k - 64)];
  wp[idx] = f2bf(v);
}

// ---- normalize (fused) + conv1d(k=3, VALID) + relu -> seq[t][b][oc] bf16.
// Loop-inverted: lane = t (64 t per chunk), wave = 16-oc slice; weights go
// through the SCALAR path (oc0 readfirstlane'd -> s_load broadcasts, K$-hot);
// x values from bank-swizzled LDS transpose buffer (i ^ (t&31), conflict-free
// on the hot read). Per-k norm factors hoisted out of the MAC loop.
__global__ __launch_bounds__(256) void k_conv(const float* __restrict__ inX,
                                              const float* __restrict__ cwT,
                                              const float* __restrict__ conv_b,
                                              u16* __restrict__ seq) {
  __shared__ float xs[66 * 128];                   // raw x rows, swizzled
  __shared__ float rn[66];
  __shared__ u16 outb[64 * 64];                    // [t_local][oc]
  const int tid = threadIdx.x;
  const int b = blockIdx.x >> 2;
  const int q = blockIdx.x & 3;
  const int wave = tid >> 6;
  const int oc0 = __builtin_amdgcn_readfirstlane(wave * 16);
  const int tl = tid & 63;                         // lane = local t
  const float4 bias4a = *reinterpret_cast<const float4*>(conv_b + oc0);
  const float4 bias4b = *reinterpret_cast<const float4*>(conv_b + oc0 + 4);
  const float4 bias4c = *reinterpret_cast<const float4*>(conv_b + oc0 + 8);
  const float4 bias4d = *reinterpret_cast<const float4*>(conv_b + oc0 + 12);

  for (int c = 0; c < 4; ++c) {
    const int t0 = (q * 4 + c) * 64;
    // ---- stage 66 rows (raw), swizzled: bank = (i ^ (row&31)) % 32
    for (int e = tid; e < 66 * 128; e += 256) {
      int tt = e >> 7, i = e & 127;
      int gt = t0 + tt;
      float v = (gt < 1024) ? inX[((size_t)b * 1024 + gt) * 128 + i] : 0.f;
      xs[tt * 128 + (i ^ (tt & 31))] = v;
    }
    __syncthreads();
    // ---- row norms (32-lane groups)
    {
      int g32 = tid >> 5, l32 = tid & 31;
      for (int r = g32; r < 66; r += 8) {
        float s = 0.f;
        #pragma unroll
        for (int jj = 0; jj < 4; ++jj) {
          float v = xs[r * 128 + ((l32 * 4 + jj) ^ (r & 31))];
          s += v * v;
        }
        #pragma unroll
        for (int d = 1; d < 32; d <<= 1) s += __shfl_xor(s, d, 32);
        if (l32 == 0) rn[r] = 1.f / fmaxf(sqrtf(s), 1e-12f);
      }
    }
    __syncthreads();
    // ---- conv: each lane = one t, 16 oc accumulators, weights via s_load
    {
      float acc[16];
      #pragma unroll
      for (int j = 0; j < 16; ++j) acc[j] = 0.f;
      const float rn0 = rn[tl], rn1 = rn[tl + 1], rn2 = rn[tl + 2];
      const int a0 = (tl + 0) * 128, m0 = (tl + 0) & 31;
      const int a1 = (tl + 1) * 128, m1 = (tl + 1) & 31;
      const int a2 = (tl + 2) * 128, m2 = (tl + 2) & 31;
      for (int i = 0; i < 128; ++i) {
        float x0 = xs[a0 + (i ^ m0)] * rn0;
        float x1 = xs[a1 + (i ^ m1)] * rn1;
        float x2 = xs[a2 + (i ^ m2)] * rn2;
        const float* w0 = cwT + (i * 3 + 0) * 64 + oc0;
        const float* w1 = cwT + (i * 3 + 1) * 64 + oc0;
        const float* w2 = cwT + (i * 3 + 2) * 64 + oc0;
        #pragma unroll
        for (int j = 0; j < 16; ++j)
          acc[j] += w0[j] * x0 + w1[j] * x1 + w2[j] * x2;
      }
      const float bj[16] = {bias4a.x, bias4a.y, bias4a.z, bias4a.w,
                            bias4b.x, bias4b.y, bias4b.z, bias4b.w,
                            bias4c.x, bias4c.y, bias4c.z, bias4c.w,
                            bias4d.x, bias4d.y, bias4d.z, bias4d.w};
      #pragma unroll
      for (int j = 0; j < 16; ++j)
        outb[tl * 64 + oc0 + j] = f2bf(fmaxf(acc[j] + bj[j], 0.f));
    }
    __syncthreads();
    // ---- coalesced store: seq[t][b][oc]
    for (int e = tid; e < 4096; e += 256) {
      int tt = e >> 6, oc = e & 63;
      int gt = t0 + tt;
      if (gt < TP) seq[((size_t)gt * 64 + b) * 64 + oc] = outb[tt * 64 + oc];
    }
    __syncthreads();
  }
}

// ---- persistent LSTM on ONE XCD, 2 independent batch-groups of 16 WGs.
// Worker path BYTE-IDENTICAL to rounds 14/16/17. NEW: 512 WGs launched (was
// 256) — each XCD gets ~64, so the designated XCD's first 32 registrants are
// workers and its REMAINING ~32 become keepers CO-RESIDENT on the worker CUs.
// Round 8's keeper test never put keepers on the worker XCD (256 WGs = exactly
// 32/XCD, all of them workers there) — per-XCD DVFS means the worker XCD's
// clock domain stayed at the floor, the ~2.6x invariant multiplier.
__global__ __launch_bounds__(256, 1) void k_lstm(const u16* __restrict__ seq,
                                                 const u16* __restrict__ wp,
                                                 const float* __restrict__ biasp,
                                                 u16* h0buf, u16* h1buf,
                                                 float* __restrict__ hfin,
                                                 unsigned* bar) {
  const int tid = threadIdx.x;
  __shared__ int s_rank;
  __shared__ __align__(16) char hl[32768];         // staged group h-half, swizzled
  __shared__ u16 ostage[32][40];                   // [batch_local][unit_local], padded

  // ---- XCD self-designation (setup only; agent-scope atomics via MALL)
  if (tid == 0) {
    unsigned xcd;
    asm volatile("s_getreg_b32 %0, hwreg(HW_REG_XCC_ID)" : "=s"(xcd));
    xcd &= 7u;
    unsigned r = __hip_atomic_fetch_add(&bar[8 + xcd], 1u, __ATOMIC_RELAXED,
                                        __HIP_MEMORY_SCOPE_AGENT);
    if (r == NWRK - 1) {
      unsigned expected = 0u;
      __hip_atomic_compare_exchange_strong(&bar[16], &expected, xcd + 1u,
                                           __ATOMIC_RELAXED, __ATOMIC_RELAXED,
                                           __HIP_MEMORY_SCOPE_AGENT);
    }
    unsigned d;
    while ((d = __hip_atomic_load(&bar[16], __ATOMIC_RELAXED,
                                  __HIP_MEMORY_SCOPE_AGENT)) == 0u)
      __builtin_amdgcn_s_sleep(8);
    s_rank = (xcd == d - 1u && r < NWRK) ? (int)r : -1;
  }
  __syncthreads();
  const int rank = s_rank;

  if (rank < 0) {
    // ---- clock keeper: dependent-FMA spin until all workers signal done.
    // With 512 WGs, ~32 of these land on the DESIGNATED XCD (2 WGs/CU with the
    // workers) and hold that clock domain at boost.
    const int lane_ = tid & 63;
    float x = (float)tid + 1.0f;
    unsigned d = 0;
    do {
      #pragma unroll
      for (int i = 0; i < 1024; ++i) x = __builtin_fmaf(x, 1.0000001f, 1.0e-30f);
      asm volatile("" :: "v"(x));                  // keep the chain live (no DCE)
      if (lane_ == 0)
        d = __hip_atomic_fetch_add(&bar[96], 0u, __ATOMIC_RELAXED,
                                   __HIP_MEMORY_SCOPE_AGENT);
      d = __shfl(d, 0);
    } while (d < NWRK);
    return;
  }

  const int wave = tid >> 6, lane = tid & 63;
  const int g   = rank >> 4;                       // batch group 0/1
  const int wgi = rank & 15;                       // index within group
  const int B0  = g * 32;                          // group's batch base
  const int U0  = wgi * 32;                        // WG's unit base
  const int mt2 = wgi * 4 + wave;                  // 0..63 within group
  const int mtA = 2 * mt2, mtB = mtA + 1;          // unit m-tiles 0..127
  const int bl  = lane & 15;                       // local batch (tile 0); +16 tile 1
  const int bA  = B0 + bl;                         // global batch (tile 0)
  const int hi  = lane >> 4;                       // 0..3
  const int koff = hi * 8;
  const int ulA = 8 * wave + hi;                   // unit-local in WG's 32-slice
  const int ulB = ulA + 4;
  const int uA  = U0 + ulA;                        // global unit ids
  const int uB  = U0 + ulB;
  const float4 biasA = *reinterpret_cast<const float4*>(biasp + mtA * 16 + hi * 4);
  const float4 biasB = *reinterpret_cast<const float4*>(biasp + mtB * 16 + hi * 4);

  // preload both weight slices: 2 x 18 k-tiles x 8 bf16/lane = 144 VGPRs
  short8 wA[18], wB[18];
  {
    const u16* wa = wp + (size_t)mtA * (18 * 512) + lane * 8;
    const u16* wb = wp + (size_t)mtB * (18 * 512) + lane * 8;
    #pragma unroll
    for (int kt = 0; kt < 18; ++kt) {
      wA[kt] = *reinterpret_cast<const short8*>(wa + kt * 512);
      wB[kt] = *reinterpret_cast<const short8*>(wb + kt * 512);
    }
  }

  unsigned* grpcnt = &bar[g * 32];                 // per-group counter (own 128B line)
  float cA0 = 0.f, cA1 = 0.f, cB0 = 0.f, cB1 = 0.f;
  f32x4 accA0, accA1, accB0, accB1;

  // LDS fragment-read constants (local rows bl / bl+16; swizzle by row&7)
  const int r0base = bl * 1024;
  const int r1base = r0base + 16 * 1024;
  const int rmask  = (bl & 7) << 4;                // (bl+16)&7 == bl&7
  const int fr_hib = hi * 16;

  // staging constants: rows p*8+strow, col-16B stcol; swizzle=(row&7)<<4=strow<<4
  const int strow = tid >> 5;                      // 0..7
  const int stcol = tid & 31;                      // 16B chunk within 512B half
  const int stswz = strow << 4;

#define XPART(T) do { \
    const u16* xt_ = seq + (size_t)(T) * 4096; \
    short8 x0a = *reinterpret_cast<const short8*>(xt_ + bA * 64 + koff); \
    short8 x1a = *reinterpret_cast<const short8*>(xt_ + (bA + 16) * 64 + koff); \
    short8 x0b = *reinterpret_cast<const short8*>(xt_ + bA * 64 + 32 + koff); \
    short8 x1b = *reinterpret_cast<const short8*>(xt_ + (bA + 16) * 64 + 32 + koff); \
    f32x4 z_ = {0.f, 0.f, 0.f, 0.f}; \
    accA0 = __builtin_amdgcn_mfma_f32_16x16x32_bf16(wA[0], x0a, z_, 0, 0, 0); \
    accA1 = __builtin_amdgcn_mfma_f32_16x16x32_bf16(wA[0], x1a, z_, 0, 0, 0); \
    accB0 = __builtin_amdgcn_mfma_f32_16x16x32_bf16(wB[0], x0a, z_, 0, 0, 0); \
    accB1 = __builtin_amdgcn_mfma_f32_16x16x32_bf16(wB[0], x1a, z_, 0, 0, 0); \
    accA0 = __builtin_amdgcn_mfma_f32_16x16x32_bf16(wA[1], x0b, accA0, 0, 0, 0); \
    accA1 = __builtin_amdgcn_mfma_f32_16x16x32_bf16(wA[1], x1b, accA1, 0, 0, 0); \
    accB0 = __builtin_amdgcn_mfma_f32_16x16x32_bf16(wB[1], x0b, accB0, 0, 0, 0); \
    accB1 = __builtin_amdgcn_mfma_f32_16x16x32_bf16(wB[1], x1b, accB1, 0, 0, 0); \
  } while (0)

  XPART(0);                                        // x-part for t=0 (h(-1)=0)

  for (int t = 0; t < TP; ++t) {
    // ---- wait for own group's h(t-1): ONE RMW per WG per poll iteration
    if (t > 0) {
      if (tid == 0) {
        const unsigned tgt = (unsigned)(16 * t);
        for (;;) {
          unsigned v = __hip_atomic_fetch_add(grpcnt, 0u, __ATOMIC_RELAXED,
                                              __HIP_MEMORY_SCOPE_WORKGROUP);
          if (v >= tgt) break;
          __builtin_amdgcn_s_sleep(1);
        }
      }
      __syncthreads();
    }

    const u16* hc = (t & 1) ? h1buf : h0buf;
    u16* hn = (t & 1) ? h0buf : h1buf;

    // ---- stage the GROUP's 32KB h-half, K-SPLIT: issue all 8 loads, wait only
    // the first-half columns (bytes 0..511 of each row), write+barrier, compute
    // kt 0..7 while the second half's latency hides; then write+barrier, kt 8..15.
    const u16* hsrc = hc + (size_t)B0 * 512;
    f32x4 va[4], vb[4];
    #pragma unroll
    for (int p = 0; p < 4; ++p)
      va[p] = load16_sc0(hsrc + (size_t)(p * 8 + strow) * 512 + stcol * 8);
    #pragma unroll
    for (int p = 0; p < 4; ++p)
      vb[p] = load16_sc0(hsrc + (size_t)(p * 8 + strow) * 512 + 256 + stcol * 8);
    asm volatile("s_waitcnt vmcnt(4)" ::: "memory");
    __builtin_amdgcn_sched_barrier(0);
    #pragma unroll
    for (int p = 0; p < 4; ++p)
      *reinterpret_cast<f32x4*>(hl + (p * 8 + strow) * 1024 +
                                ((stcol * 16) ^ stswz)) = va[p];
    __syncthreads();

    // ---- kt 0..7 (columns 0..511B, region A)
    #pragma unroll
    for (int kt = 0; kt < 8; ++kt) {
      int off = (kt * 64 + fr_hib) ^ rmask;
      short8 b0 = *reinterpret_cast<const short8*>(hl + r0base + off);
      short8 b1 = *reinterpret_cast<const short8*>(hl + r1base + off);
      accA0 = __builtin_amdgcn_mfma_f32_16x16x32_bf16(wA[kt + 2], b0, accA0, 0, 0, 0);
      accA1 = __builtin_amdgcn_mfma_f32_16x16x32_bf16(wA[kt + 2], b1, accA1, 0, 0, 0);
      accB0 = __builtin_amdgcn_mfma_f32_16x16x32_bf16(wB[kt + 2], b0, accB0, 0, 0, 0);
      accB1 = __builtin_amdgcn_mfma_f32_16x16x32_bf16(wB[kt + 2], b1, accB1, 0, 0, 0);
    }

    // ---- write second half (long arrived), barrier, kt 8..15 (region B)
    asm volatile("s_waitcnt vmcnt(0)" ::: "memory");
    __builtin_amdgcn_sched_barrier(0);
    #pragma unroll
    for (int p = 0; p < 4; ++p)
      *reinterpret_cast<f32x4*>(hl + (p * 8 + strow) * 1024 + 512 +
                                ((stcol * 16) ^ stswz)) = vb[p];
    __syncthreads();
    #pragma unroll
    for (int kt = 8; kt < 16; ++kt) {
      int off = (kt * 64 + fr_hib) ^ rmask;
      short8 b0 = *reinterpret_cast<const short8*>(hl + r0base + off);
      short8 b1 = *reinterpret_cast<const short8*>(hl + r1base + off);
      accA0 = __builtin_amdgcn_mfma_f32_16x16x32_bf16(wA[kt + 2], b0, accA0, 0, 0, 0);
      accA1 = __builtin_amdgcn_mfma_f32_16x16x32_bf16(wA[kt + 2], b1, accA1, 0, 0, 0);
      accB0 = __builtin_amdgcn_mfma_f32_16x16x32_bf16(wB[kt + 2], b0, accB0, 0, 0, 0);
      accB1 = __builtin_amdgcn_mfma_f32_16x16x32_bf16(wB[kt + 2], b1, accB1, 0, 0, 0);
    }

    // ---- gates (i,f,g,o in acc[0..3] of each lane, per mt x batch-tile)
    float iA0 = sigmoidf_(accA0[0] + biasA.x);
    float fA0 = sigmoidf_(accA0[1] + biasA.y);
    float gA0 = tanhf_(accA0[2] + biasA.z);
    float oA0 = sigmoidf_(accA0[3] + biasA.w);
    cA0 = fA0 * cA0 + iA0 * gA0;
    float hvA0 = oA0 * tanhf_(cA0);
    float iA1 = sigmoidf_(accA1[0] + biasA.x);
    float fA1 = sigmoidf_(accA1[1] + biasA.y);
    float gA1 = tanhf_(accA1[2] + biasA.z);
    float oA1 = sigmoidf_(accA1[3] + biasA.w);
    cA1 = fA1 * cA1 + iA1 * gA1;
    float hvA1 = oA1 * tanhf_(cA1);
    float iB0 = sigmoidf_(accB0[0] + biasB.x);
    float fB0 = sigmoidf_(accB0[1] + biasB.y);
    float gB0 = tanhf_(accB0[2] + biasB.z);
    float oB0 = sigmoidf_(accB0[3] + biasB.w);
    cB0 = fB0 * cB0 + iB0 * gB0;
    float hvB0 = oB0 * tanhf_(cB0);
    float iB1 = sigmoidf_(accB1[0] + biasB.x);
    float fB1 = sigmoidf_(accB1[1] + biasB.y);
    float gB1 = tanhf_(accB1[2] + biasB.z);
    float oB1 = sigmoidf_(accB1[3] + biasB.w);
    cB1 = fB1 * cB1 + iB1 * gB1;
    float hvB1 = oB1 * tanhf_(cB1);

    // ---- stage h slice (32 batches x 32 units) in padded LDS
    ostage[bl][ulA]      = f2bf(hvA0);
    ostage[bl + 16][ulA] = f2bf(hvA1);
    ostage[bl][ulB]      = f2bf(hvB0);
    ostage[bl + 16][ulB] = f2bf(hvB1);
    if (t == TP - 1) {
      hfin[bA * 512 + uA]        = hvA0;
      hfin[(bA + 16) * 512 + uA] = hvA1;
      hfin[bA * 512 + uB]        = hvB0;
      hfin[(bA + 16) * 512 + uB] = hvB1;
    }
    __syncthreads();

    // ---- coalesced sc0 h stores: 128 threads x 16B into XCD L2
    if (tid < 128) {
      int b_l = tid >> 2, q = tid & 3;
      f32x4 val = *reinterpret_cast<const f32x4*>(&ostage[b_l][q * 8]);
      store16_sc0(hn + (size_t)(B0 + b_l) * 512 + U0 + q * 8, val);
    }
    asm volatile("s_waitcnt vmcnt(0)" ::: "memory");
    __syncthreads();                               // all waves' stores drained

    // ---- signal own group: ONE atomic RMW per WG
    if (tid == 0)
      __hip_atomic_fetch_add(grpcnt, 1u, __ATOMIC_RELAXED, __HIP_MEMORY_SCOPE_WORKGROUP);

    // ---- x-part prefetch for t+1 (plain cached loads) overlaps others' polls
    if (t + 1 < TP) XPART(t + 1);
  }
#undef XPART

  // ---- tell the clock keepers we're done (MALL-scope RMW, cross-XCD visible)
  if (tid == 0)
    __hip_atomic_fetch_add(&bar[96], 1u, __ATOMIC_RELAXED, __HIP_MEMORY_SCOPE_AGENT);
}

// ---- final linear: out[b][o] = h . lin_w[o] + lin_b[o]  (fp32, float4 reads)
__global__ void k_fc(const float* __restrict__ hfin, const float* __restrict__ lin_w,
                     const float* __restrict__ lin_b, float* __restrict__ out) {
  int b = blockIdx.x, o = threadIdx.x;             // 128 threads
  const float4* hp = reinterpret_cast<const float4*>(hfin + b * 512);
  const float4* wq = reinterpret_cast<const float4*>(lin_w + o * 512);
  float s = lin_b[o];
  #pragma unroll 8
  for (int j = 0; j < 128; ++j) {
    float4 h4 = hp[j], w4 = wq[j];
    s += h4.x * w4.x + h4.y * w4.y + h4.z * w4.z + h4.w * w4.w;
  }
  out[b * 128 + o] = s;
}

extern "C" void kernel_launch(void* const* d_in, const int* in_sizes, int n_in,
                              void* d_out, int out_size, void* d_ws, size_t ws_size,
                              hipStream_t stream) {
  const float* inX    = (const float*)d_in[0];
  const float* conv_w = (const float*)d_in[2];
  const float* conv_b = (const float*)d_in[3];
  const float* w_ih   = (const float*)d_in[4];
  const float* w_hh   = (const float*)d_in[5];
  const float* b_ih   = (const float*)d_in[6];
  const float* b_hh   = (const float*)d_in[7];
  const float* lin_w  = (const float*)d_in[8];
  const float* lin_b  = (const float*)d_in[9];
  float* out = (float*)d_out;
  char* ws = (char*)d_ws;
  u16*      wpack = (u16*)(ws + OFF_WPACK);
  u16*      seq   = (u16*)(ws + OFF_SEQ);
  float*    biasp = (float*)(ws + OFF_BIAS);
  u16*      h0b   = (u16*)(ws + OFF_H0);
  u16*      h1b   = (u16*)(ws + OFF_H1);
  float*    hfin  = (float*)(ws + OFF_HFIN);
  unsigned* bar   = (unsigned*)(ws + OFF_BAR);
  float*    cwT   = (float*)(ws + OFF_CWT);

  k_init<<<dim3(128), dim3(256), 0, stream>>>(b_ih, b_hh, conv_w, biasp,
                                              (unsigned*)(ws + OFF_H0), bar, cwT);
  k_pack<<<dim3(4608), dim3(256), 0, stream>>>(w_ih, w_hh, wpack);
  k_conv<<<dim3(256), dim3(256), 0, stream>>>(inX, cwT, conv_b, seq);
  k_lstm<<<dim3(512), dim3(256), 0, stream>>>(seq, wpack, biasp, h0b, h1b, hfin, bar);
  k_fc<<<dim3(64), dim3(128), 0, stream>>>(hfin, lin_w, lin_b, out);
}